// Round 10
// baseline (133.764 us; speedup 1.0000x reference)
//
#include <hip/hip_runtime.h>

typedef _Float16 f16;
typedef __attribute__((ext_vector_type(8))) _Float16 f16x8;
typedef __attribute__((ext_vector_type(4))) float f32x4;

namespace {
constexpr int B   = 2;
constexpr int CIN = 64;
constexpr int H   = 32;
constexpr int W   = 192;
constexpr int DM  = 32;
constexpr int NH  = 8;
constexpr int C   = 4;
constexpr int QS  = 24;
constexpr int FL  = 8;
constexpr int T   = 192;
constexpr int TP  = T + 2 * FL;   // 208
constexpr int M   = T / QS;       // 8
constexpr int F   = 2 * FL + QS;  // 40
constexpr int HF  = H * F;        // 1280 keys/group
constexpr int WP  = 196;          // padded conv row (784B pitch)
constexpr int HWP = H * WP;       // 6272

// ---- workspace (f32 units), lifetime-overlapped --------------------------
// prep(XP,pads,zr) -> qkv(XP->Q,K,V) -> pack_q(Q->QT over XP) ->
// pack_kv(K,V->KVIK,VT32; VT32 tail clobbers dead Q) -> attn(->O over K)
// -> out_conv(O->out)
constexpr size_t KVIK_OFF = 0;        // 327,680 f32-eq (128*1280 uint2, f16x4 K)
constexpr size_t QT_OFF   = 327680;   // 196,608 f32-eq (128*768 uint2, f16x4 Q)
constexpr size_t VT_OFF   = 524288;   // 655,360 f32 (128*4*1280 f32 V) -> ends 1,179,648
constexpr size_t XP_OFF   = 0;        // 802,816 (phase 1 only; aliased above)
constexpr size_t Q_OFF    = 802816;   // 393,216 (dead after pack_q)
constexpr size_t K_OFF    = 1196032;  // 425,984
constexpr size_t V_OFF    = 1622016;  // 425,984
constexpr size_t O_OFF    = K_OFF;    // 401,408 (K dead after pack_kv)
constexpr size_t ZR_OFF   = 2048000;  // 256 zeros
// high-water 2,048,256 f32 = 8.19 MB

// strides of the faithful as_strided-bug gather (uses T=192, not TP=208!)
constexpr int S0 = NH * C * H * T; // 196608
constexpr int S1 = C * H * T;      // 24576
constexpr int S2 = H * T;          // 6144
constexpr int S3 = T;              // 192
}

// round-to-nearest f16 pair pack (cold path)
__device__ inline unsigned pk16rn(float a, float b) {
  union { f16 h[2]; unsigned u; } c;
  c.h[0] = (f16)a; c.h[1] = (f16)b;
  return c.u;
}

// ---- prep: pad x rows to 196 + zero K/V pad cols + zero page -------------
__global__ __launch_bounds__(256) void prep_k(const float* __restrict__ x,
                                              float* __restrict__ ws) {
  int bid = blockIdx.x;
  int tid = threadIdx.x;
  if (bid < 4096) {
    if (tid < WP) {
      float v = (tid >= 1 && tid <= W) ? x[(size_t)bid * W + (tid - 1)] : 0.f;
      ws[XP_OFF + (size_t)bid * WP + tid] = v;
    }
  } else if (bid < 4224) {
    int t = (bid - 4096) * 256 + tid;
    int row = t >> 4;
    int p = t & 15;
    int col = (p < 8) ? p : (192 + p);
    size_t addr = (size_t)row * TP + col;
    ws[K_OFF + addr] = 0.f;
    ws[V_OFF + addr] = 0.f;
  } else {
    ws[ZR_OFF + tid] = 0.f;
  }
}

// ---- fused q/k/v conv3x3: 4 x-positions per thread -----------------------
__global__ __launch_bounds__(192) void qkv_conv_k(
    const float* __restrict__ qw, const float* __restrict__ qb,
    const float* __restrict__ kw, const float* __restrict__ kb,
    const float* __restrict__ vw, const float* __restrict__ vb,
    float* __restrict__ ws) {
  int bid = blockIdx.x;
  int yq = bid & 7;
  int co = (bid >> 3) & 31;
  int b  = bid >> 8;
  int tid = threadIdx.x;
  int yl = tid / 48;
  int xq = tid - yl * 48;
  int y  = yq * 4 + yl;
  int xp = xq * 4;

  const float* zr  = ws + ZR_OFF;
  const float* xpb = ws + XP_OFF + (size_t)b * CIN * HWP;

  const float* p0 = (y > 0)     ? xpb + (y - 1) * WP + xp : zr + xp;
  const float* p1 = xpb + y * WP + xp;
  const float* p2 = (y < H - 1) ? xpb + (y + 1) * WP + xp : zr + xp;
  int st0 = (y > 0)     ? HWP : 0;
  int st2 = (y < H - 1) ? HWP : 0;

  const float* wq = qw + co * (CIN * 9);
  const float* wk = kw + co * (CIN * 9);
  const float* wv = vw + co * (CIN * 9);

  float q0b = qb[co], k0b = kb[co], v0b = vb[co];
  float Aq[4] = {q0b, q0b, q0b, q0b};
  float Ak[4] = {k0b, k0b, k0b, k0b};
  float Av[4] = {v0b, v0b, v0b, v0b};

#pragma unroll 2
  for (int ci = 0; ci < CIN; ++ci) {
    float4 a4 = *reinterpret_cast<const float4*>(p0);
    float2 a2 = *reinterpret_cast<const float2*>(p0 + 4);
    float4 b4 = *reinterpret_cast<const float4*>(p1);
    float2 b2 = *reinterpret_cast<const float2*>(p1 + 4);
    float4 c4 = *reinterpret_cast<const float4*>(p2);
    float2 c2 = *reinterpret_cast<const float2*>(p2 + 4);
    float av_[6] = {a4.x, a4.y, a4.z, a4.w, a2.x, a2.y};
    float bv_[6] = {b4.x, b4.y, b4.z, b4.w, b2.x, b2.y};
    float cv_[6] = {c4.x, c4.y, c4.z, c4.w, c2.x, c2.y};
#pragma unroll
    for (int dx = 0; dx < 3; ++dx) {
      float wq0 = wq[dx], wq1 = wq[3 + dx], wq2 = wq[6 + dx];
      float wk0 = wk[dx], wk1 = wk[3 + dx], wk2 = wk[6 + dx];
      float wv0 = wv[dx], wv1 = wv[3 + dx], wv2 = wv[6 + dx];
#pragma unroll
      for (int o = 0; o < 4; ++o) {
        float xa = av_[o + dx], xb = bv_[o + dx], xc = cv_[o + dx];
        Aq[o] = fmaf(xa, wq0, Aq[o]); Aq[o] = fmaf(xb, wq1, Aq[o]); Aq[o] = fmaf(xc, wq2, Aq[o]);
        Ak[o] = fmaf(xa, wk0, Ak[o]); Ak[o] = fmaf(xb, wk1, Ak[o]); Ak[o] = fmaf(xc, wk2, Ak[o]);
        Av[o] = fmaf(xa, wv0, Av[o]); Av[o] = fmaf(xb, wv1, Av[o]); Av[o] = fmaf(xc, wv2, Av[o]);
      }
    }
    p0 += st0; p1 += HWP; p2 += st2;
    wq += 9; wk += 9; wv += 9;
  }

  *reinterpret_cast<float4*>(ws + Q_OFF + ((size_t)(b * DM + co) * H + y) * T + xp) =
      make_float4(Aq[0], Aq[1], Aq[2], Aq[3]);
  int h = co >> 2, c4i = co & 3;
  size_t pa = ((size_t)((b * NH + h) * C + c4i) * H + y) * TP + FL + xp;
  *reinterpret_cast<float4*>(ws + K_OFF + pa) = make_float4(Ak[0], Ak[1], Ak[2], Ak[3]);
  *reinterpret_cast<float4*>(ws + V_OFF + pa) = make_float4(Av[0], Av[1], Av[2], Av[3]);
}

// ---- pack Q -> QT f16x4 per (g,row), scale 0.5 folded (RTN) --------------
__global__ __launch_bounds__(256) void pack_q_k(float* __restrict__ ws) {
  int t = blockIdx.x * 256 + threadIdx.x;       // < 98304
  int g = t / 768, row = t - g * 768;
  int b = g >> 6, h = (g >> 3) & 7, m = g & 7;
  int hh = row / QS, qi = row - hh * QS;
  const float* qb = ws + Q_OFF;
  size_t qidx = ((size_t)(b * DM + h * C) * H + hh) * T + m * QS + qi;
  const float SC = 0.5f;
  uint2 o;
  o.x = pk16rn(qb[qidx] * SC,             qb[qidx + H * T] * SC);
  o.y = pk16rn(qb[qidx + 2 * H * T] * SC, qb[qidx + 3 * H * T] * SC);
  reinterpret_cast<uint2*>(ws + QT_OFF)[t] = o;
}

// ---- pack K,V (drift-gather): K -> f16x4/key, V -> f32 [g][c][key] -------
__global__ __launch_bounds__(256) void pack_kv_k(float* __restrict__ ws) {
  int t = blockIdx.x * 256 + threadIdx.x;       // < 163840
  int g = t / HF, key = t - g * HF;
  int b = g >> 6, h = (g >> 3) & 7, m = g & 7;
  int hh = key / F, f = key - hh * F;
  int base = b * S0 + h * S1 + hh * S3 + m * QS + f;
  const float* kp = ws + K_OFF;
  const float* vp = ws + V_OFF;
  float k0 = kp[base], k1 = kp[base + S2], k2 = kp[base + 2 * S2], k3 = kp[base + 3 * S2];
  float v0 = vp[base], v1 = vp[base + S2], v2 = vp[base + 2 * S2], v3 = vp[base + 3 * S2];
  uint2 o; o.x = pk16rn(k0, k1); o.y = pk16rn(k2, k3);
  reinterpret_cast<uint2*>(ws + KVIK_OFF)[t] = o;
  float* vt = ws + VT_OFF;
  size_t vg = (size_t)g * 4 * HF;
  vt[vg + key]          = v0;
  vt[vg + HF + key]     = v1;
  vt[vg + 2 * HF + key] = v2;
  vt[vg + 3 * HF + key] = v3;
}

// ---- attention: MFMA QK (verified C/D map) + per-lane scalar softmax/PV --
// Wave = 16 qrows x 1280 keys. mfma(K,Q): lane(l15,q2) reg r =
// logit[key=key0+4q2+r][qrow=rt*16+l15]. exp in f32; PV per-lane with f32 V;
// cross-q2 shfl_xor reduction; lane writes channel c=q2.
__global__ __launch_bounds__(256) void attn_k(float* __restrict__ ws) {
  const uint2* kvik = reinterpret_cast<const uint2*>(ws + KVIK_OFF);
  const uint2* qt   = reinterpret_cast<const uint2*>(ws + QT_OFF);
  const float* vt   = ws + VT_OFF;
  float* ob = ws + O_OFF;

  int g   = blockIdx.x;                         // 0..127
  int rb  = blockIdx.y;                         // 0..11
  int b = g >> 6, h = (g >> 3) & 7, m = g & 7;
  int tid  = threadIdx.x;
  int lane = tid & 63;
  int wid  = tid >> 6;                          // 0..3
  int rt   = rb * 4 + wid;                      // 0..47
  int l15  = lane & 15;
  int q2   = lane >> 4;                         // 0..3

  union F8 { f16x8 h; unsigned u[4]; uint2 d[2]; };

  // Q B-frag: q2==0 lanes carry [q0..q3] at k-slots 0..3; everything else 0
  F8 qf; qf.d[0] = make_uint2(0, 0); qf.d[1] = make_uint2(0, 0);
  if (q2 == 0) qf.d[0] = qt[(size_t)g * 768 + rt * 16 + l15];

  const uint2*  kbase = kvik + (size_t)g * HF;
  const float4* v0 = reinterpret_cast<const float4*>(vt + ((size_t)g * 4 + 0) * HF);
  const float4* v1 = reinterpret_cast<const float4*>(vt + ((size_t)g * 4 + 1) * HF);
  const float4* v2 = reinterpret_cast<const float4*>(vt + ((size_t)g * 4 + 2) * HF);
  const float4* v3 = reinterpret_cast<const float4*>(vt + ((size_t)g * 4 + 3) * HF);

  f32x4 z4 = {0.f, 0.f, 0.f, 0.f};
  float o0 = 0.f, o1 = 0.f, o2 = 0.f, o3 = 0.f, s = 0.f;

  for (int kt = 0; kt < 40; ++kt) {
    int key0 = kt * 32;
    F8 kf1, kf2;
    kf1.d[0] = make_uint2(0, 0); kf1.d[1] = make_uint2(0, 0);
    kf2.d[0] = make_uint2(0, 0); kf2.d[1] = make_uint2(0, 0);
    if (q2 == 0) {
      kf1.d[0] = kbase[key0 + l15];
      kf2.d[0] = kbase[key0 + 16 + l15];
    }
    f32x4 lg1 = __builtin_amdgcn_mfma_f32_16x16x32_f16(kf1.h, qf.h, z4, 0, 0, 0);
    f32x4 lg2 = __builtin_amdgcn_mfma_f32_16x16x32_f16(kf2.h, qf.h, z4, 0, 0, 0);

    // this lane's keys: key0+4q2+r (lg1) and key0+16+4q2+r (lg2)
    int j1 = kt * 8 + q2;                       // float4 idx: keys key0+4q2..+3
    int j2 = kt * 8 + 4 + q2;                   // keys key0+16+4q2..+3
    float4 va0 = v0[j1], vb0 = v0[j2];
    float4 va1 = v1[j1], vb1 = v1[j2];
    float4 va2 = v2[j1], vb2 = v2[j2];
    float4 va3 = v3[j1], vb3 = v3[j2];

#pragma unroll
    for (int r = 0; r < 4; ++r) {
      float e1 = __expf(lg1[r]);
      float e2 = __expf(lg2[r]);
      s += e1 + e2;
      o0 = fmaf(e1, (&va0.x)[r], o0); o0 = fmaf(e2, (&vb0.x)[r], o0);
      o1 = fmaf(e1, (&va1.x)[r], o1); o1 = fmaf(e2, (&vb1.x)[r], o1);
      o2 = fmaf(e1, (&va2.x)[r], o2); o2 = fmaf(e2, (&vb2.x)[r], o2);
      o3 = fmaf(e1, (&va3.x)[r], o3); o3 = fmaf(e2, (&vb3.x)[r], o3);
    }
  }

  // reduce across the 4 q2 groups (same l15 = same qrow)
  o0 += __shfl_xor(o0, 16); o0 += __shfl_xor(o0, 32);
  o1 += __shfl_xor(o1, 16); o1 += __shfl_xor(o1, 32);
  o2 += __shfl_xor(o2, 16); o2 += __shfl_xor(o2, 32);
  o3 += __shfl_xor(o3, 16); o3 += __shfl_xor(o3, 32);
  s  += __shfl_xor(s, 16);  s  += __shfl_xor(s, 32);

  // lane (l15, q2) writes channel c = q2 of qrow rt*16 + l15
  float oc = (q2 == 0) ? o0 : (q2 == 1) ? o1 : (q2 == 2) ? o2 : o3;
  float ov = oc / s;
  int row = rt * 16 + l15;
  int hh = row / QS, qi = row - hh * QS;
  size_t ob_ = (((size_t)(b * DM + h * C + q2) * H + hh) * WP) + 1 + m * QS + qi;
  ob[ob_] = ov;
  if (m == 0 && qi == 0)          ob[ob_ - 1] = 0.f;
  if (m == M - 1 && qi == QS - 1) ob[ob_ + 1] = 0.f;
}

// ---- output conv3x3 (32 -> 64): 2 co x 4 x per thread --------------------
__global__ __launch_bounds__(192) void out_conv_k(const float* __restrict__ ws,
                                                  const float* __restrict__ ow,
                                                  float* __restrict__ out) {
  int bid = blockIdx.x;
  int yq = bid & 7;
  int cp = (bid >> 3) & 31;
  int b  = bid >> 8;
  int tid = threadIdx.x;
  int yl = tid / 48;
  int xq = tid - yl * 48;
  int y  = yq * 4 + yl;
  int xp = xq * 4;

  const float* zr  = ws + ZR_OFF;
  const float* obb = ws + O_OFF + (size_t)b * DM * HWP;

  const float* p0 = (y > 0)     ? obb + (y - 1) * WP + xp : zr + xp;
  const float* p1 = obb + y * WP + xp;
  const float* p2 = (y < H - 1) ? obb + (y + 1) * WP + xp : zr + xp;
  int st0 = (y > 0)     ? HWP : 0;
  int st2 = (y < H - 1) ? HWP : 0;

  int co0 = cp * 2;
  const float* w0 = ow + (size_t)co0 * (DM * 9);
  const float* w1 = w0 + DM * 9;
  float A0[4] = {0.f, 0.f, 0.f, 0.f};
  float A1[4] = {0.f, 0.f, 0.f, 0.f};

#pragma unroll 2
  for (int ci = 0; ci < DM; ++ci) {
    float4 a4 = *reinterpret_cast<const float4*>(p0);
    float2 a2 = *reinterpret_cast<const float2*>(p0 + 4);
    float4 b4 = *reinterpret_cast<const float4*>(p1);
    float2 b2 = *reinterpret_cast<const float2*>(p1 + 4);
    float4 c4 = *reinterpret_cast<const float4*>(p2);
    float2 c2 = *reinterpret_cast<const float2*>(p2 + 4);
    float av_[6] = {a4.x, a4.y, a4.z, a4.w, a2.x, a2.y};
    float bv_[6] = {b4.x, b4.y, b4.z, b4.w, b2.x, b2.y};
    float cv_[6] = {c4.x, c4.y, c4.z, c4.w, c2.x, c2.y};
#pragma unroll
    for (int dx = 0; dx < 3; ++dx) {
      float u0 = w0[dx], u1 = w0[3 + dx], u2 = w0[6 + dx];
      float t0 = w1[dx], t1 = w1[3 + dx], t2 = w1[6 + dx];
#pragma unroll
      for (int o = 0; o < 4; ++o) {
        float xa = av_[o + dx], xb = bv_[o + dx], xc = cv_[o + dx];
        A0[o] = fmaf(xa, u0, A0[o]); A0[o] = fmaf(xb, u1, A0[o]); A0[o] = fmaf(xc, u2, A0[o]);
        A1[o] = fmaf(xa, t0, A1[o]); A1[o] = fmaf(xb, t1, A1[o]); A1[o] = fmaf(xc, t2, A1[o]);
      }
    }
    p0 += st0; p1 += HWP; p2 += st2;
    w0 += 9; w1 += 9;
  }

  size_t ob0 = ((size_t)(b * 64 + co0) * H + y) * W + xp;
  *reinterpret_cast<float4*>(out + ob0)         = make_float4(A0[0], A0[1], A0[2], A0[3]);
  *reinterpret_cast<float4*>(out + ob0 + H * W) = make_float4(A1[0], A1[1], A1[2], A1[3]);
}

extern "C" void kernel_launch(void* const* d_in, const int* in_sizes, int n_in,
                              void* d_out, int out_size, void* d_ws, size_t ws_size,
                              hipStream_t stream) {
  const float* x  = (const float*)d_in[0];
  const float* qw = (const float*)d_in[1];
  const float* qb = (const float*)d_in[2];
  const float* kw = (const float*)d_in[3];
  const float* kb = (const float*)d_in[4];
  const float* vw = (const float*)d_in[5];
  const float* vb = (const float*)d_in[6];
  const float* ow = (const float*)d_in[7];
  float* out = (float*)d_out;
  float* ws  = (float*)d_ws;

  hipLaunchKernelGGL(prep_k,     dim3(4225), dim3(256), 0, stream, x, ws);
  hipLaunchKernelGGL(qkv_conv_k, dim3(512),  dim3(192), 0, stream,
                     qw, qb, kw, kb, vw, vb, ws);
  hipLaunchKernelGGL(pack_q_k,   dim3(384),  dim3(256), 0, stream, ws);
  hipLaunchKernelGGL(pack_kv_k,  dim3(640),  dim3(256), 0, stream, ws);
  hipLaunchKernelGGL(attn_k,     dim3(128, 12), dim3(256), 0, stream, ws);
  hipLaunchKernelGGL(out_conv_k, dim3(512),  dim3(192), 0, stream, ws, ow, out);
}

// Round 11
// 101.427 us; speedup vs baseline: 1.3188x; 1.3188x over previous
//
#include <hip/hip_runtime.h>

#if __has_builtin(__builtin_amdgcn_exp2f)
#define EXP2F(x) __builtin_amdgcn_exp2f(x)
#else
#define EXP2F(x) exp2f(x)
#endif

namespace {
constexpr int B   = 2;
constexpr int CIN = 64;
constexpr int H   = 32;
constexpr int W   = 192;
constexpr int DM  = 32;
constexpr int NH  = 8;
constexpr int C   = 4;
constexpr int QS  = 24;
constexpr int FL  = 8;
constexpr int T   = 192;
constexpr int TP  = T + 2 * FL;   // 208
constexpr int M   = T / QS;       // 8
constexpr int F   = 2 * FL + QS;  // 40
constexpr int HF  = H * F;        // 1280 keys/group
constexpr int JC  = HF / 4;       // 320 keys per wave-chunk
constexpr int WP  = 196;          // padded conv row (784B pitch)
constexpr int HWP = H * WP;       // 6272

// ---- workspace layout (floats), lifetime-overlapped (r4-proven) ----------
// prep(XP,pads,zr) -> qkv(XP->Q,K,V) -> build_kv(K,V -> KVI over XP)
// -> attn(Q,KVI -> O over K) -> out_conv(O->out)
constexpr size_t XP_OFF  = 0;                          // 802,816
constexpr size_t KVI_OFF = 0;                          // 1,310,720 (XP dead)
constexpr size_t Q_OFF   = 1310720;                    // 393,216
constexpr size_t K_OFF   = Q_OFF + 393216;             // 1,703,936 ; 425,984
constexpr size_t V_OFF   = K_OFF + 425984;             // 2,129,920 ; 425,984
constexpr size_t O_OFF   = K_OFF;                      // 401,408 (K dead)
constexpr size_t ZR_OFF  = V_OFF + 425984;             // 2,555,904 ; 256 zeros
// total = 2,556,160 floats = 10.22 MB

// strides of the faithful as_strided-bug gather (uses T=192, not TP=208!)
constexpr int S0 = NH * C * H * T; // 196608
constexpr int S1 = C * H * T;      // 24576
constexpr int S2 = H * T;          // 6144
constexpr int S3 = T;              // 192

constexpr float QSC = 0.72134752044f;  // 0.5 * log2(e), folded into Q for exp2
}

// ---- prep: pad x rows to 196 + zero K/V pad cols + zero page -------------
__global__ __launch_bounds__(256) void prep_k(const float* __restrict__ x,
                                              float* __restrict__ ws) {
  int bid = blockIdx.x;
  int tid = threadIdx.x;
  if (bid < 4096) {                       // x rows: (b*64+ci)*32+y
    if (tid < WP) {
      float v = (tid >= 1 && tid <= W) ? x[(size_t)bid * W + (tid - 1)] : 0.f;
      ws[XP_OFF + (size_t)bid * WP + tid] = v;
    }
  } else if (bid < 4224) {                // K/V pad cols: 2048 rows x 16
    int t = (bid - 4096) * 256 + tid;
    int row = t >> 4;
    int p = t & 15;
    int col = (p < 8) ? p : (192 + p);
    size_t addr = (size_t)row * TP + col;
    ws[K_OFF + addr] = 0.f;
    ws[V_OFF + addr] = 0.f;
  } else {
    ws[ZR_OFF + tid] = 0.f;
  }
}

// ---- fused q/k/v conv3x3: 4 x-positions per thread -----------------------
__global__ __launch_bounds__(192) void qkv_conv_k(
    const float* __restrict__ qw, const float* __restrict__ qb,
    const float* __restrict__ kw, const float* __restrict__ kb,
    const float* __restrict__ vw, const float* __restrict__ vb,
    float* __restrict__ ws) {
  int bid = blockIdx.x;
  int yq = bid & 7;
  int co = (bid >> 3) & 31;
  int b  = bid >> 8;
  int tid = threadIdx.x;
  int yl = tid / 48;
  int xq = tid - yl * 48;
  int y  = yq * 4 + yl;
  int xp = xq * 4;

  const float* zr  = ws + ZR_OFF;
  const float* xpb = ws + XP_OFF + (size_t)b * CIN * HWP;

  const float* p0 = (y > 0)     ? xpb + (y - 1) * WP + xp : zr + xp;
  const float* p1 = xpb + y * WP + xp;
  const float* p2 = (y < H - 1) ? xpb + (y + 1) * WP + xp : zr + xp;
  int st0 = (y > 0)     ? HWP : 0;
  int st2 = (y < H - 1) ? HWP : 0;

  const float* wq = qw + co * (CIN * 9);
  const float* wk = kw + co * (CIN * 9);
  const float* wv = vw + co * (CIN * 9);

  float q0b = qb[co], k0b = kb[co], v0b = vb[co];
  float Aq[4] = {q0b, q0b, q0b, q0b};
  float Ak[4] = {k0b, k0b, k0b, k0b};
  float Av[4] = {v0b, v0b, v0b, v0b};

#pragma unroll 2
  for (int ci = 0; ci < CIN; ++ci) {
    float4 a4 = *reinterpret_cast<const float4*>(p0);
    float2 a2 = *reinterpret_cast<const float2*>(p0 + 4);
    float4 b4 = *reinterpret_cast<const float4*>(p1);
    float2 b2 = *reinterpret_cast<const float2*>(p1 + 4);
    float4 c4 = *reinterpret_cast<const float4*>(p2);
    float2 c2 = *reinterpret_cast<const float2*>(p2 + 4);
    float av_[6] = {a4.x, a4.y, a4.z, a4.w, a2.x, a2.y};
    float bv_[6] = {b4.x, b4.y, b4.z, b4.w, b2.x, b2.y};
    float cv_[6] = {c4.x, c4.y, c4.z, c4.w, c2.x, c2.y};
#pragma unroll
    for (int dx = 0; dx < 3; ++dx) {
      float wq0 = wq[dx], wq1 = wq[3 + dx], wq2 = wq[6 + dx];
      float wk0 = wk[dx], wk1 = wk[3 + dx], wk2 = wk[6 + dx];
      float wv0 = wv[dx], wv1 = wv[3 + dx], wv2 = wv[6 + dx];
#pragma unroll
      for (int o = 0; o < 4; ++o) {
        float xa = av_[o + dx], xb = bv_[o + dx], xc = cv_[o + dx];
        Aq[o] = fmaf(xa, wq0, Aq[o]); Aq[o] = fmaf(xb, wq1, Aq[o]); Aq[o] = fmaf(xc, wq2, Aq[o]);
        Ak[o] = fmaf(xa, wk0, Ak[o]); Ak[o] = fmaf(xb, wk1, Ak[o]); Ak[o] = fmaf(xc, wk2, Ak[o]);
        Av[o] = fmaf(xa, wv0, Av[o]); Av[o] = fmaf(xb, wv1, Av[o]); Av[o] = fmaf(xc, wv2, Av[o]);
      }
    }
    p0 += st0; p1 += HWP; p2 += st2;
    wq += 9; wk += 9; wv += 9;
  }

  *reinterpret_cast<float4*>(ws + Q_OFF + ((size_t)(b * DM + co) * H + y) * T + xp) =
      make_float4(Aq[0], Aq[1], Aq[2], Aq[3]);
  int h = co >> 2, c4i = co & 3;
  size_t pa = ((size_t)((b * NH + h) * C + c4i) * H + y) * TP + FL + xp;
  *reinterpret_cast<float4*>(ws + K_OFF + pa) = make_float4(Ak[0], Ak[1], Ak[2], Ak[3]);
  *reinterpret_cast<float4*>(ws + V_OFF + pa) = make_float4(Av[0], Av[1], Av[2], Av[3]);
}

// ---- build interleaved KV windows: kvi[g][j][k0..k3,v0..v3] --------------
__global__ __launch_bounds__(256) void build_kv_k(float* __restrict__ ws) {
  const float* kp = ws + K_OFF;
  const float* vp = ws + V_OFF;
  float* kvi = ws + KVI_OFF;
  int t = blockIdx.x * 256 + threadIdx.x;       // < 1,310,720
  int c  = t & 7;
  int gj = t >> 3;
  int g  = gj / HF;
  int j  = gj - g * HF;
  int b = g >> 6, h = (g >> 3) & 7, m = g & 7;
  int hh = j / F, f = j - hh * F;
  int ci = c & 3;
  const float* src = (c < 4) ? kp : vp;
  int addr = b * S0 + h * S1 + ci * S2 + hh * S3 + m * QS + f;
  kvi[t] = src[addr];
}

// ---- attention: scalar r4 structure + 2-chain ILP + native exp2 ----------
// block = 4 j-chunk waves x 64 rows; grid (128 groups, 12 row-blocks)
__global__ __launch_bounds__(256) void attn_k(float* __restrict__ ws) {
  const float* qbuf = ws + Q_OFF;
  const float* kvi  = ws + KVI_OFF;
  float*       ob   = ws + O_OFF;

  int g  = blockIdx.x;                          // 0..127
  int rb = blockIdx.y;                          // 0..11
  int b = g >> 6, h = (g >> 3) & 7, m = g & 7;
  int tid = threadIdx.x;
  int row = tid & 63;
  int jc  = __builtin_amdgcn_readfirstlane(tid >> 6);

  int r  = rb * 64 + row;                       // 0..767
  int hh = r / QS, qi = r - hh * QS;
  size_t qidx = (((size_t)(b * DM + h * C) * H + hh) * T) + m * QS + qi;
  float q0 = qbuf[qidx]             * QSC;
  float q1 = qbuf[qidx + H * T]     * QSC;
  float q2 = qbuf[qidx + 2 * H * T] * QSC;
  float q3 = qbuf[qidx + 3 * H * T] * QSC;

  const float* kvp = kvi + ((size_t)g * HF + (size_t)jc * JC) * 8;

  // two independent chains (even/odd keys) for ILP
  float sA = 0.f, sB = 0.f;
  float a0 = 0.f, a1 = 0.f, a2 = 0.f, a3 = 0.f;
  float b0_ = 0.f, b1_ = 0.f, b2_ = 0.f, b3_ = 0.f;
#pragma unroll 4
  for (int j = 0; j < JC; j += 2) {
    float4 kA = *reinterpret_cast<const float4*>(kvp + j * 8);
    float4 vA = *reinterpret_cast<const float4*>(kvp + j * 8 + 4);
    float4 kB = *reinterpret_cast<const float4*>(kvp + j * 8 + 8);
    float4 vB = *reinterpret_cast<const float4*>(kvp + j * 8 + 12);
    float lA = fmaf(q0, kA.x, fmaf(q1, kA.y, fmaf(q2, kA.z, q3 * kA.w)));
    float lB = fmaf(q0, kB.x, fmaf(q1, kB.y, fmaf(q2, kB.z, q3 * kB.w)));
    float eA = EXP2F(lA);
    float eB = EXP2F(lB);
    sA += eA; sB += eB;
    a0 = fmaf(eA, vA.x, a0);  b0_ = fmaf(eB, vB.x, b0_);
    a1 = fmaf(eA, vA.y, a1);  b1_ = fmaf(eB, vB.y, b1_);
    a2 = fmaf(eA, vA.z, a2);  b2_ = fmaf(eB, vB.z, b2_);
    a3 = fmaf(eA, vA.w, a3);  b3_ = fmaf(eB, vB.w, b3_);
  }
  float s  = sA + sB;
  float o0 = a0 + b0_, o1 = a1 + b1_, o2 = a2 + b2_, o3 = a3 + b3_;

  __shared__ float red[4][64][5];
  red[jc][row][0] = s;
  red[jc][row][1] = o0;
  red[jc][row][2] = o1;
  red[jc][row][3] = o2;
  red[jc][row][4] = o3;
  __syncthreads();

  if (tid < 64) {                               // row == tid here
    float S = 0.f, O0 = 0.f, O1 = 0.f, O2 = 0.f, O3 = 0.f;
#pragma unroll
    for (int cx = 0; cx < 4; ++cx) {
      S  += red[cx][tid][0];
      O0 += red[cx][tid][1];
      O1 += red[cx][tid][2];
      O2 += red[cx][tid][3];
      O3 += red[cx][tid][4];
    }
    float inv = 1.0f / S;
    // padded O: row stride WP=196, interior offset +1
    size_t obase = (((size_t)(b * DM + h * C) * H + hh) * WP) + 1 + m * QS + qi;
    ob[obase]            = O0 * inv;
    ob[obase + HWP]      = O1 * inv;
    ob[obase + 2 * HWP]  = O2 * inv;
    ob[obase + 3 * HWP]  = O3 * inv;
    if (m == 0 && qi == 0) {                    // zero pad col 0
      ob[obase - 1] = 0.f; ob[obase - 1 + HWP] = 0.f;
      ob[obase - 1 + 2 * HWP] = 0.f; ob[obase - 1 + 3 * HWP] = 0.f;
    }
    if (m == M - 1 && qi == QS - 1) {           // zero pad col 193
      ob[obase + 1] = 0.f; ob[obase + 1 + HWP] = 0.f;
      ob[obase + 1 + 2 * HWP] = 0.f; ob[obase + 1 + 3 * HWP] = 0.f;
    }
  }
}

// ---- output conv3x3 (32 -> 64): 2 co x 4 x per thread --------------------
__global__ __launch_bounds__(192) void out_conv_k(const float* __restrict__ ws,
                                                  const float* __restrict__ ow,
                                                  float* __restrict__ out) {
  int bid = blockIdx.x;
  int yq = bid & 7;
  int cp = (bid >> 3) & 31;
  int b  = bid >> 8;
  int tid = threadIdx.x;
  int yl = tid / 48;
  int xq = tid - yl * 48;
  int y  = yq * 4 + yl;
  int xp = xq * 4;

  const float* zr  = ws + ZR_OFF;
  const float* obb = ws + O_OFF + (size_t)b * DM * HWP;

  const float* p0 = (y > 0)     ? obb + (y - 1) * WP + xp : zr + xp;
  const float* p1 = obb + y * WP + xp;
  const float* p2 = (y < H - 1) ? obb + (y + 1) * WP + xp : zr + xp;
  int st0 = (y > 0)     ? HWP : 0;
  int st2 = (y < H - 1) ? HWP : 0;

  int co0 = cp * 2;
  const float* w0 = ow + (size_t)co0 * (DM * 9);
  const float* w1 = w0 + DM * 9;
  float A0[4] = {0.f, 0.f, 0.f, 0.f};
  float A1[4] = {0.f, 0.f, 0.f, 0.f};

#pragma unroll 2
  for (int ci = 0; ci < DM; ++ci) {
    float4 a4 = *reinterpret_cast<const float4*>(p0);
    float2 a2 = *reinterpret_cast<const float2*>(p0 + 4);
    float4 b4 = *reinterpret_cast<const float4*>(p1);
    float2 b2 = *reinterpret_cast<const float2*>(p1 + 4);
    float4 c4 = *reinterpret_cast<const float4*>(p2);
    float2 c2 = *reinterpret_cast<const float2*>(p2 + 4);
    float av_[6] = {a4.x, a4.y, a4.z, a4.w, a2.x, a2.y};
    float bv_[6] = {b4.x, b4.y, b4.z, b4.w, b2.x, b2.y};
    float cv_[6] = {c4.x, c4.y, c4.z, c4.w, c2.x, c2.y};
#pragma unroll
    for (int dx = 0; dx < 3; ++dx) {
      float u0 = w0[dx], u1 = w0[3 + dx], u2 = w0[6 + dx];
      float t0 = w1[dx], t1 = w1[3 + dx], t2 = w1[6 + dx];
#pragma unroll
      for (int o = 0; o < 4; ++o) {
        float xa = av_[o + dx], xb = bv_[o + dx], xc = cv_[o + dx];
        A0[o] = fmaf(xa, u0, A0[o]); A0[o] = fmaf(xb, u1, A0[o]); A0[o] = fmaf(xc, u2, A0[o]);
        A1[o] = fmaf(xa, t0, A1[o]); A1[o] = fmaf(xb, t1, A1[o]); A1[o] = fmaf(xc, t2, A1[o]);
      }
    }
    p0 += st0; p1 += HWP; p2 += st2;
    w0 += 9; w1 += 9;
  }

  size_t ob0 = ((size_t)(b * 64 + co0) * H + y) * W + xp;
  *reinterpret_cast<float4*>(out + ob0)         = make_float4(A0[0], A0[1], A0[2], A0[3]);
  *reinterpret_cast<float4*>(out + ob0 + H * W) = make_float4(A1[0], A1[1], A1[2], A1[3]);
}

extern "C" void kernel_launch(void* const* d_in, const int* in_sizes, int n_in,
                              void* d_out, int out_size, void* d_ws, size_t ws_size,
                              hipStream_t stream) {
  const float* x  = (const float*)d_in[0];
  const float* qw = (const float*)d_in[1];
  const float* qb = (const float*)d_in[2];
  const float* kw = (const float*)d_in[3];
  const float* kb = (const float*)d_in[4];
  const float* vw = (const float*)d_in[5];
  const float* vb = (const float*)d_in[6];
  const float* ow = (const float*)d_in[7];
  float* out = (float*)d_out;
  float* ws  = (float*)d_ws;

  hipLaunchKernelGGL(prep_k,     dim3(4225), dim3(256), 0, stream, x, ws);
  hipLaunchKernelGGL(qkv_conv_k, dim3(512),  dim3(192), 0, stream,
                     qw, qb, kw, kb, vw, vb, ws);
  hipLaunchKernelGGL(build_kv_k, dim3(5120), dim3(256), 0, stream, ws);
  hipLaunchKernelGGL(attn_k,     dim3(128, 12), dim3(256), 0, stream, ws);
  hipLaunchKernelGGL(out_conv_k, dim3(512),  dim3(192), 0, stream, ws, ow, out);
}